// Round 14
// baseline (305.916 us; speedup 1.0000x reference)
//
#include <hip/hip_runtime.h>

#define WAVE 64
#define BUCKET_CAP 5632
#define NBUF 400
#define EPB 4096

typedef __attribute__((ext_vector_type(8))) short short8v;
typedef __attribute__((ext_vector_type(4))) float floatx4;
typedef __attribute__((ext_vector_type(2))) float floatx2;

__device__ __forceinline__ ushort f2bf(float f) {
    union { float f; unsigned u; } v; v.f = f;
    unsigned r = v.u + 0x7FFF + ((v.u >> 16) & 1);
    return (ushort)(r >> 16);
}
__device__ __forceinline__ float bf2f(ushort u) {
    union { unsigned u; float f; } v; v.u = ((unsigned)u) << 16;
    return v.f;
}

// ---------------- init: zero scratch + transpose/convert both W (fused) ----------------

__global__ void k_init(int* __restrict__ zreg, int nzero, int zblocks,
                       const float* __restrict__ W1, const float* __restrict__ W2,
                       ushort* __restrict__ T1, ushort* __restrict__ T2) {
    int b = blockIdx.x;
    if (b < zblocks) {
        int i = b * 256 + threadIdx.x;
        if (i < nzero) zreg[i] = 0;
    } else {
        const float* W = (b == zblocks) ? W1 : W2;
        ushort* T = (b == zblocks) ? T1 : T2;
        for (int i = threadIdx.x; i < 16384; i += 256) {
            int k = i >> 7, n = i & 127;
            T[n * 128 + k] = f2bf(W[k * 128 + n]);
        }
    }
}

// ---------------- CSR build (two-level bucket sort) ----------------

__global__ __launch_bounds__(256) void k_bucket(const int* __restrict__ src,
                                                const int* __restrict__ dst,
                                                int E, int N, int B,
                                                int* __restrict__ bcnt,
                                                int* __restrict__ bucket) {
    __shared__ int cnt[NBUF];
    __shared__ int gbase[NBUF];
    int t = threadIdx.x;
    long base = (long)blockIdx.x * EPB;

    for (int k = t; k < NBUF; k += 256) cnt[k] = 0;
    __syncthreads();

    int pay[16], bk[16];
#pragma unroll
    for (int k = 0; k < 16; ++k) {
        long i = base + (long)k * 256 + t;
        bk[k] = -1;
        if (i < (long)E + N) {
            int d, s;
            if (i < E) { d = dst[i]; s = src[i]; }
            else       { d = (int)(i - E); s = d; }
            int b = d >> 8;
            bk[k] = b;
            pay[k] = ((d & 255) << 17) | s;
            atomicAdd(&cnt[b], 1);
        }
    }
    __syncthreads();

    for (int k = t; k < NBUF; k += 256) {
        int c = cnt[k];
        gbase[k] = (c > 0 && k < B) ? atomicAdd(&bcnt[k], c) : 0;
        cnt[k] = 0;
    }
    __syncthreads();

#pragma unroll
    for (int k = 0; k < 16; ++k) {
        if (bk[k] >= 0) {
            int lpos = atomicAdd(&cnt[bk[k]], 1);
            int pos = gbase[bk[k]] + lpos;
            if (pos < BUCKET_CAP)
                bucket[(size_t)bk[k] * BUCKET_CAP + pos] = pay[k];
        }
    }
}

__global__ void k_bscan(const int* __restrict__ bcnt, int* __restrict__ bbase,
                        int B, int Etot, int* __restrict__ offs, int N) {
    __shared__ int sh[512];
    int t = threadIdx.x;
    int v = (t < B) ? bcnt[t] : 0;
    sh[t] = v;
    __syncthreads();
    for (int o = 1; o < 512; o <<= 1) {
        int u = (t >= o) ? sh[t - o] : 0;
        __syncthreads();
        sh[t] += u;
        __syncthreads();
    }
    if (t < B) bbase[t] = sh[t] - v;
    if (t == 0) offs[N] = Etot;
}

__global__ __launch_bounds__(256) void k_csr(const int* __restrict__ bcnt,
                                             const int* __restrict__ bbase,
                                             const int* __restrict__ bucket,
                                             int* __restrict__ offs,
                                             int* __restrict__ csr, int N) {
    __shared__ int ebuf[BUCKET_CAP];
    __shared__ int cnt[256], sc[256], cur[256];
    int b = blockIdx.x, t = threadIdx.x;
    int n = bcnt[b]; if (n > BUCKET_CAP) n = BUCKET_CAP;
    int base = bbase[b];
    cnt[t] = 0;
    __syncthreads();
    const int* bk = bucket + (size_t)b * BUCKET_CAP;
    for (int k = t; k < n; k += 256) {
        int e = bk[k];
        ebuf[k] = e;
        atomicAdd(&cnt[e >> 17], 1);
    }
    __syncthreads();
    sc[t] = cnt[t];
    __syncthreads();
    for (int o = 1; o < 256; o <<= 1) {
        int u = (t >= o) ? sc[t - o] : 0;
        __syncthreads();
        sc[t] += u;
        __syncthreads();
    }
    int loff = sc[t] - cnt[t];
    int node = (b << 8) + t;
    if (node < N) offs[node] = base + loff;
    cur[t] = loff;
    __syncthreads();
    for (int k = t; k < n; k += 256) {
        int e = ebuf[k];
        int pos = base + atomicAdd(&cur[e >> 17], 1);
        csr[pos] = e & 0x1FFFF;
    }
}

// ---------------- MFMA GEMM (BM=64): Cf8[M x 128](fp8) = A[M x 128] @ W ----------------

template<bool AF32>
__global__ __launch_bounds__(256) void k_gemm_mfma(const void* __restrict__ Ain,
                                                   const ushort* __restrict__ Wt,
                                                   const float* __restrict__ a_s,
                                                   const float* __restrict__ a_d,
                                                   unsigned char* __restrict__ Cf8,
                                                   float* __restrict__ es,
                                                   float* __restrict__ ed, int M) {
    __shared__ ushort As[64][128];
    __shared__ ushort Ws[128][128];
    int t = threadIdx.x;
    int lane = t & 63, wid = t >> 6;
    int row0 = blockIdx.x * 64;

    {
        short8v w[8];
#pragma unroll
        for (int it = 0; it < 8; ++it) {
            int idx = it * 256 + t;
            w[it] = *(const short8v*)&Wt[(idx >> 4) * 128 + (idx & 15) * 8];
        }
#pragma unroll
        for (int it = 0; it < 8; ++it) {
            int idx = it * 256 + t;
            int r = idx >> 4, ch = idx & 15;
            *(short8v*)&Ws[r][(ch ^ (r & 15)) * 8] = w[it];
        }
    }
    {
        short8v a[4];
#pragma unroll
        for (int it = 0; it < 4; ++it) {
            int idx = it * 256 + t;
            int r = idx >> 4, ch = idx & 15;
            int gr = row0 + r;
            short8v u = {0, 0, 0, 0, 0, 0, 0, 0};
            if (gr < M) {
                if (AF32) {
                    const float* A = (const float*)Ain;
                    float4 f0 = *(const float4*)&A[(size_t)gr * 128 + ch * 8];
                    float4 f1 = *(const float4*)&A[(size_t)gr * 128 + ch * 8 + 4];
                    u[0] = (short)f2bf(f0.x); u[1] = (short)f2bf(f0.y);
                    u[2] = (short)f2bf(f0.z); u[3] = (short)f2bf(f0.w);
                    u[4] = (short)f2bf(f1.x); u[5] = (short)f2bf(f1.y);
                    u[6] = (short)f2bf(f1.z); u[7] = (short)f2bf(f1.w);
                } else {
                    const ushort* A = (const ushort*)Ain;
                    u = *(const short8v*)&A[(size_t)gr * 128 + ch * 8];
                }
            }
            a[it] = u;
        }
#pragma unroll
        for (int it = 0; it < 4; ++it) {
            int idx = it * 256 + t;
            int r = idx >> 4, ch = idx & 15;
            *(short8v*)&As[r][(ch ^ (r & 15)) * 8] = a[it];
        }
    }
    __syncthreads();

    int mrow = wid * 16;
    int col = lane & 15;
    int kg = lane >> 4;
    floatx4 acc[8] = {};

#pragma unroll
    for (int ks = 0; ks < 4; ++ks) {
        int chb = ks * 4 + kg;
        int r0 = mrow + col;
        short8v a0 = *(short8v*)&As[r0][(chb ^ (r0 & 15)) * 8];
        short8v b[8];
#pragma unroll
        for (int ni = 0; ni < 8; ++ni) {
            int rn = ni * 16 + col;
            b[ni] = *(short8v*)&Ws[rn][(chb ^ (rn & 15)) * 8];
        }
#pragma unroll
        for (int ni = 0; ni < 8; ++ni)
            acc[ni] = __builtin_amdgcn_mfma_f32_16x16x32_bf16(b[ni], a0, acc[ni], 0, 0, 0);
    }

    int node = row0 + mrow + col;
    bool ok = node < M;
    float esp = 0.f, edp = 0.f;
#pragma unroll
    for (int ni = 0; ni < 8; ++ni) {
        floatx4 v = acc[ni];
        float4 sv = *(const float4*)(a_s + ni * 16 + kg * 4);
        float4 dv = *(const float4*)(a_d + ni * 16 + kg * 4);
        esp += v[0] * sv.x + v[1] * sv.y + v[2] * sv.z + v[3] * sv.w;
        edp += v[0] * dv.x + v[1] * dv.y + v[2] * dv.z + v[3] * dv.w;
        int lo = __builtin_amdgcn_cvt_pk_fp8_f32(v[0], v[1], 0, false);
        int dw = __builtin_amdgcn_cvt_pk_fp8_f32(v[2], v[3], lo, true);
        if (ok) *(int*)&Cf8[(size_t)node * 128 + ni * 16 + kg * 4] = dw;
    }
    esp += __shfl_xor(esp, 16); esp += __shfl_xor(esp, 32);
    edp += __shfl_xor(edp, 16); edp += __shfl_xor(edp, 32);
    if (ok && kg == 0) { es[node] = esp; ed[node] = edp; }
}

// ---------------- per-node softmax + aggregation (wave per node) ----------------
// FINAL=false: writes bf16 rows to out. FINAL=true (layer 2): skips the row
// store and pools directly — block-level LDS f32-atomic reduction (4 nodes),
// one 128-float global-atomic flush per block into psums (graph-boundary
// blocks use direct per-node atomics for the odd-graph nodes).

template<bool FINAL>
__global__ __launch_bounds__(256) void k_aggregate(const unsigned char* __restrict__ hf8,
                                                   const float* __restrict__ es,
                                                   const float* __restrict__ ed,
                                                   const int* __restrict__ csr_src,
                                                   const int* __restrict__ offs,
                                                   const float* __restrict__ bias,
                                                   ushort* __restrict__ out,
                                                   const int* __restrict__ batch,
                                                   float* __restrict__ psums, int N) {
    __shared__ __align__(16) float2 pe[4][64];
    __shared__ float bsum[128];
    __shared__ int g0s;
    int tid = threadIdx.x;
    int wid  = tid >> 6;
    int lane = tid & 63;
    int w = (blockIdx.x * 256 + tid) >> 6;
    bool active = w < N;
    if (!FINAL && !active) return;

    if (FINAL) {
        for (int i = tid; i < 128; i += 256) bsum[i] = 0.f;
        if (tid == 0) g0s = batch[blockIdx.x * 4 < N ? blockIdx.x * 4 : N - 1];
        __syncthreads();
    }

    int beg = 0, end = 0;
    float edi = 0.f;
    if (active) { beg = offs[w]; end = offs[w + 1]; edi = ed[w]; }
    int grp = lane >> 4, fc = lane & 15;
    const unsigned char* hbase = hf8 + fc * 8;

    float s_lane = 0.f;
    float acc[8] = {0.f, 0.f, 0.f, 0.f, 0.f, 0.f, 0.f, 0.f};

    for (int tb = beg; tb < end; tb += WAVE) {
        int cnt = end - tb; if (cnt > WAVE) cnt = WAVE;

        float p = 0.f;
        int sj = 0;
        if (lane < cnt) {
            sj = csr_src[tb + lane];
            float t = es[sj] + edi;
            float e = (t > 0.f) ? t : 0.2f * t;
            p = __expf(e);
        }
        s_lane += p;
        pe[wid][lane] = make_float2(p, __int_as_float(sj << 7));
        asm volatile("s_waitcnt lgkmcnt(0)" ::: "memory");

        __builtin_amdgcn_s_setprio(1);
        int cnt4 = (cnt + 3) & ~3;
        for (int k = 0; k < cnt4; k += 4) {
            float2 pr = pe[wid][k + grp];
            float p_ = pr.x;
            int off = __float_as_int(pr.y);
            uint2 v = *(const uint2*)(hbase + off);
            floatx2 f0 = __builtin_amdgcn_cvt_pk_f32_fp8(v.x, false);
            floatx2 f1 = __builtin_amdgcn_cvt_pk_f32_fp8(v.x, true);
            floatx2 f2 = __builtin_amdgcn_cvt_pk_f32_fp8(v.y, false);
            floatx2 f3 = __builtin_amdgcn_cvt_pk_f32_fp8(v.y, true);
            acc[0] += p_ * f0.x; acc[1] += p_ * f0.y;
            acc[2] += p_ * f1.x; acc[3] += p_ * f1.y;
            acc[4] += p_ * f2.x; acc[5] += p_ * f2.y;
            acc[6] += p_ * f3.x; acc[7] += p_ * f3.y;
        }
        __builtin_amdgcn_s_setprio(0);
    }

    float s = s_lane;
#pragma unroll
    for (int o = 32; o; o >>= 1) s += __shfl_xor(s, o);

#pragma unroll
    for (int i = 0; i < 8; ++i) {
        acc[i] += __shfl_xor(acc[i], 16);
        acc[i] += __shfl_xor(acc[i], 32);
    }

    float o_[8];
    bool emit = (grp == 0) && active;
    if (emit) {
        float rinv = 1.f / s;
        float4 b0 = *(const float4*)(bias + fc * 8);
        float4 b1 = *(const float4*)(bias + fc * 8 + 4);
        o_[0] = fmaxf(acc[0] * rinv + b0.x, 0.f);
        o_[1] = fmaxf(acc[1] * rinv + b0.y, 0.f);
        o_[2] = fmaxf(acc[2] * rinv + b0.z, 0.f);
        o_[3] = fmaxf(acc[3] * rinv + b0.w, 0.f);
        o_[4] = fmaxf(acc[4] * rinv + b1.x, 0.f);
        o_[5] = fmaxf(acc[5] * rinv + b1.y, 0.f);
        o_[6] = fmaxf(acc[6] * rinv + b1.z, 0.f);
        o_[7] = fmaxf(acc[7] * rinv + b1.w, 0.f);
    }

    if (!FINAL) {
        if (emit) {
            uint4 pk;
            pk.x = (unsigned)f2bf(o_[0]) | ((unsigned)f2bf(o_[1]) << 16);
            pk.y = (unsigned)f2bf(o_[2]) | ((unsigned)f2bf(o_[3]) << 16);
            pk.z = (unsigned)f2bf(o_[4]) | ((unsigned)f2bf(o_[5]) << 16);
            pk.w = (unsigned)f2bf(o_[6]) | ((unsigned)f2bf(o_[7]) << 16);
            *(uint4*)(out + (size_t)w * 128 + fc * 8) = pk;
        }
    } else {
        if (emit) {
            int g = batch[w];
            if (g == g0s) {
#pragma unroll
                for (int i = 0; i < 8; ++i) atomicAdd(&bsum[fc * 8 + i], o_[i]);
            } else {
#pragma unroll
                for (int i = 0; i < 8; ++i) atomicAdd(&psums[g * 128 + fc * 8 + i], o_[i]);
            }
        }
        __syncthreads();
        if (tid < 128) {
            float v = bsum[tid];
            if (v != 0.f) atomicAdd(&psums[g0s * 128 + tid], v);
        }
    }
}

// ---------------- head: mean-pool finalize + concat + linear ----------------

__global__ __launch_bounds__(64) void k_head(const float* __restrict__ sums,
                                             const int* __restrict__ batch,
                                             const float* __restrict__ gf,
                                             const float* __restrict__ linW,
                                             const float* __restrict__ linb,
                                             float* __restrict__ out, int N) {
    int g = blockIdx.x, t = threadIdx.x;
    __shared__ float feat[144];
    int lo, hi;
    { int a = 0, b = N; while (a < b) { int mid = (a + b) >> 1; if (batch[mid] < g) a = mid + 1; else b = mid; } lo = a; }
    { int a = lo, b = N; while (a < b) { int mid = (a + b) >> 1; if (batch[mid] < g + 1) a = mid + 1; else b = mid; } hi = a; }
    float c = fmaxf((float)(hi - lo), 1.f);
    for (int k = t; k < 128; k += 64) feat[k] = sums[g * 128 + k] / c;
    if (t < 16) feat[128 + t] = gf[g * 16 + t];
    __syncthreads();
    if (t < 10) {
        float acc = linb[t];
        for (int k = 0; k < 144; ++k) acc += feat[k] * linW[k * 10 + t];
        out[g * 10 + t] = acc;
    }
}

// ---------------- launch ----------------

extern "C" void kernel_launch(void* const* d_in, const int* in_sizes, int n_in,
                              void* d_out, int out_size, void* d_ws, size_t ws_size,
                              hipStream_t stream) {
    const float* x    = (const float*)d_in[0];
    const int*   eidx = (const int*)d_in[1];
    const int*   batch = (const int*)d_in[2];
    const float* gf   = (const float*)d_in[3];
    const float* W1   = (const float*)d_in[4];
    const float* as1  = (const float*)d_in[5];
    const float* ad1  = (const float*)d_in[6];
    const float* b1   = (const float*)d_in[7];
    const float* W2   = (const float*)d_in[8];
    const float* as2  = (const float*)d_in[9];
    const float* ad2  = (const float*)d_in[10];
    const float* b2   = (const float*)d_in[11];
    const float* linW = (const float*)d_in[12];
    const float* linb = (const float*)d_in[13];
    float* out = (float*)d_out;

    const int N = in_sizes[0] / 128;
    const int E = in_sizes[1] / 2;
    const int Etot = E + N;
    const int B = (N + 255) >> 8;
    const int* srcp = eidx;
    const int* dstp = eidx + E;

    char* ws = (char*)d_ws;
    size_t off = 0;
    auto alloc = [&](size_t bytes) -> void* {
        void* p = ws + off;
        off += (bytes + 255) & ~(size_t)255;
        return p;
    };
    unsigned char* hAf8 = (unsigned char*)alloc((size_t)N * 128);  // GEMM out (fp8, gather-only)
    ushort* hBb   = (ushort*)alloc((size_t)N * 128 * 2);           // layer-1 aggregate out (bf16)
    float*  esed  = (float*)alloc((size_t)2 * N * 4);
    float*  es = esed, *ed = esed + N;
    ushort* Wt1   = (ushort*)alloc(16384 * 2);
    ushort* Wt2   = (ushort*)alloc(16384 * 2);
    int*    offs  = (int*)alloc((size_t)(N + 1) * 4);
    int*    bbase = (int*)alloc((size_t)B * 4);
    int*    bucket= (int*)alloc((size_t)B * BUCKET_CAP * 4);
    int*    csr   = (int*)alloc((size_t)Etot * 4);
    int nzero = B + 64 * 128;
    int*    zreg  = (int*)alloc((size_t)nzero * 4);
    int*    bcnt  = zreg;
    float*  psums = (float*)(zreg + B);

    // ---- init (zero scratch + W transpose) ----
    int zblocks = (nzero + 255) / 256;
    k_init<<<zblocks + 2, 256, 0, stream>>>(zreg, nzero, zblocks, W1, W2, Wt1, Wt2);

    // ---- CSR build ----
    k_bucket<<<(Etot + EPB - 1) / EPB, 256, 0, stream>>>(srcp, dstp, E, N, B, bcnt, bucket);
    k_bscan<<<1, 512, 0, stream>>>(bcnt, bbase, B, Etot, offs, N);
    k_csr<<<B, 256, 0, stream>>>(bcnt, bbase, bucket, offs, csr, N);

    int gblocks = (N + 63) / 64;
    int wblocks = ((size_t)N * 64 + 255) / 256;

    // ---- layer 1 ----
    k_gemm_mfma<true><<<gblocks, 256, 0, stream>>>(x, Wt1, as1, ad1, hAf8, es, ed, N);
    k_aggregate<false><<<wblocks, 256, 0, stream>>>(hAf8, es, ed, csr, offs, b1, hBb,
                                                    batch, psums, N);

    // ---- layer 2 (pooling fused into aggregate epilogue) ----
    k_gemm_mfma<false><<<gblocks, 256, 0, stream>>>(hBb, Wt2, as2, ad2, hAf8, es, ed, N);
    k_aggregate<true><<<wblocks, 256, 0, stream>>>(hAf8, es, ed, csr, offs, b2, nullptr,
                                                   batch, psums, N);

    // ---- head ----
    k_head<<<64, 64, 0, stream>>>(psums, batch, gf, linW, linb, out, N);
}

// Round 15
// 244.273 us; speedup vs baseline: 1.2524x; 1.2524x over previous
//
#include <hip/hip_runtime.h>

#define WAVE 64
#define BUCKET_CAP 5632
#define NBUF 400
#define EPB 4096
#define PCHUNK 32

typedef __attribute__((ext_vector_type(8))) short short8v;
typedef __attribute__((ext_vector_type(4))) float floatx4;
typedef __attribute__((ext_vector_type(2))) float floatx2;

__device__ __forceinline__ ushort f2bf(float f) {
    union { float f; unsigned u; } v; v.f = f;
    unsigned r = v.u + 0x7FFF + ((v.u >> 16) & 1);
    return (ushort)(r >> 16);
}
__device__ __forceinline__ float bf2f(ushort u) {
    union { unsigned u; float f; } v; v.u = ((unsigned)u) << 16;
    return v.f;
}

// ---------------- init: zero scratch + transpose/convert both W (fused) ----------------

__global__ void k_init(int* __restrict__ zreg, int nzero, int zblocks,
                       const float* __restrict__ W1, const float* __restrict__ W2,
                       ushort* __restrict__ T1, ushort* __restrict__ T2) {
    int b = blockIdx.x;
    if (b < zblocks) {
        int i = b * 256 + threadIdx.x;
        if (i < nzero) zreg[i] = 0;
    } else {
        const float* W = (b == zblocks) ? W1 : W2;
        ushort* T = (b == zblocks) ? T1 : T2;
        for (int i = threadIdx.x; i < 16384; i += 256) {
            int k = i >> 7, n = i & 127;
            T[n * 128 + k] = f2bf(W[k * 128 + n]);
        }
    }
}

// ---------------- CSR build (two-level bucket sort) ----------------

__global__ __launch_bounds__(256) void k_bucket(const int* __restrict__ src,
                                                const int* __restrict__ dst,
                                                int E, int N, int B,
                                                int* __restrict__ bcnt,
                                                int* __restrict__ bucket) {
    __shared__ int cnt[NBUF];
    __shared__ int gbase[NBUF];
    int t = threadIdx.x;
    long base = (long)blockIdx.x * EPB;

    for (int k = t; k < NBUF; k += 256) cnt[k] = 0;
    __syncthreads();

    int pay[16], bk[16];
#pragma unroll
    for (int k = 0; k < 16; ++k) {
        long i = base + (long)k * 256 + t;
        bk[k] = -1;
        if (i < (long)E + N) {
            int d, s;
            if (i < E) { d = dst[i]; s = src[i]; }
            else       { d = (int)(i - E); s = d; }
            int b = d >> 8;
            bk[k] = b;
            pay[k] = ((d & 255) << 17) | s;
            atomicAdd(&cnt[b], 1);
        }
    }
    __syncthreads();

    for (int k = t; k < NBUF; k += 256) {
        int c = cnt[k];
        gbase[k] = (c > 0 && k < B) ? atomicAdd(&bcnt[k], c) : 0;
        cnt[k] = 0;
    }
    __syncthreads();

#pragma unroll
    for (int k = 0; k < 16; ++k) {
        if (bk[k] >= 0) {
            int lpos = atomicAdd(&cnt[bk[k]], 1);
            int pos = gbase[bk[k]] + lpos;
            if (pos < BUCKET_CAP)
                bucket[(size_t)bk[k] * BUCKET_CAP + pos] = pay[k];
        }
    }
}

__global__ void k_bscan(const int* __restrict__ bcnt, int* __restrict__ bbase,
                        int B, int Etot, int* __restrict__ offs, int N) {
    __shared__ int sh[512];
    int t = threadIdx.x;
    int v = (t < B) ? bcnt[t] : 0;
    sh[t] = v;
    __syncthreads();
    for (int o = 1; o < 512; o <<= 1) {
        int u = (t >= o) ? sh[t - o] : 0;
        __syncthreads();
        sh[t] += u;
        __syncthreads();
    }
    if (t < B) bbase[t] = sh[t] - v;
    if (t == 0) offs[N] = Etot;
}

__global__ __launch_bounds__(256) void k_csr(const int* __restrict__ bcnt,
                                             const int* __restrict__ bbase,
                                             const int* __restrict__ bucket,
                                             int* __restrict__ offs,
                                             int* __restrict__ csr, int N) {
    __shared__ int ebuf[BUCKET_CAP];
    __shared__ int cnt[256], sc[256], cur[256];
    int b = blockIdx.x, t = threadIdx.x;
    int n = bcnt[b]; if (n > BUCKET_CAP) n = BUCKET_CAP;
    int base = bbase[b];
    cnt[t] = 0;
    __syncthreads();
    const int* bk = bucket + (size_t)b * BUCKET_CAP;
    for (int k = t; k < n; k += 256) {
        int e = bk[k];
        ebuf[k] = e;
        atomicAdd(&cnt[e >> 17], 1);
    }
    __syncthreads();
    sc[t] = cnt[t];
    __syncthreads();
    for (int o = 1; o < 256; o <<= 1) {
        int u = (t >= o) ? sc[t - o] : 0;
        __syncthreads();
        sc[t] += u;
        __syncthreads();
    }
    int loff = sc[t] - cnt[t];
    int node = (b << 8) + t;
    if (node < N) offs[node] = base + loff;
    cur[t] = loff;
    __syncthreads();
    for (int k = t; k < n; k += 256) {
        int e = ebuf[k];
        int pos = base + atomicAdd(&cur[e >> 17], 1);
        csr[pos] = e & 0x1FFFF;
    }
}

// ---------------- MFMA GEMM (BM=64): Cf8[M x 128](fp8) = A[M x 128] @ W ----------------
// 48KB LDS -> 3 blocks/CU. Staging loads batched into regs before LDS writes.
// Swapped-operand MFMA: lane holds 4 consecutive features of one node.

template<bool AF32>
__global__ __launch_bounds__(256) void k_gemm_mfma(const void* __restrict__ Ain,
                                                   const ushort* __restrict__ Wt,
                                                   const float* __restrict__ a_s,
                                                   const float* __restrict__ a_d,
                                                   unsigned char* __restrict__ Cf8,
                                                   float* __restrict__ es,
                                                   float* __restrict__ ed, int M) {
    __shared__ ushort As[64][128];
    __shared__ ushort Ws[128][128];
    int t = threadIdx.x;
    int lane = t & 63, wid = t >> 6;
    int row0 = blockIdx.x * 64;

    // ---- stage W: 8 chunks/thread, all loads issued before writes ----
    {
        short8v w[8];
#pragma unroll
        for (int it = 0; it < 8; ++it) {
            int idx = it * 256 + t;
            w[it] = *(const short8v*)&Wt[(idx >> 4) * 128 + (idx & 15) * 8];
        }
#pragma unroll
        for (int it = 0; it < 8; ++it) {
            int idx = it * 256 + t;
            int r = idx >> 4, ch = idx & 15;
            *(short8v*)&Ws[r][(ch ^ (r & 15)) * 8] = w[it];
        }
    }
    // ---- stage A: 4 chunks/thread ----
    {
        short8v a[4];
#pragma unroll
        for (int it = 0; it < 4; ++it) {
            int idx = it * 256 + t;
            int r = idx >> 4, ch = idx & 15;
            int gr = row0 + r;
            short8v u = {0, 0, 0, 0, 0, 0, 0, 0};
            if (gr < M) {
                if (AF32) {
                    const float* A = (const float*)Ain;
                    float4 f0 = *(const float4*)&A[(size_t)gr * 128 + ch * 8];
                    float4 f1 = *(const float4*)&A[(size_t)gr * 128 + ch * 8 + 4];
                    u[0] = (short)f2bf(f0.x); u[1] = (short)f2bf(f0.y);
                    u[2] = (short)f2bf(f0.z); u[3] = (short)f2bf(f0.w);
                    u[4] = (short)f2bf(f1.x); u[5] = (short)f2bf(f1.y);
                    u[6] = (short)f2bf(f1.z); u[7] = (short)f2bf(f1.w);
                } else {
                    const ushort* A = (const ushort*)Ain;
                    u = *(const short8v*)&A[(size_t)gr * 128 + ch * 8];
                }
            }
            a[it] = u;
        }
#pragma unroll
        for (int it = 0; it < 4; ++it) {
            int idx = it * 256 + t;
            int r = idx >> 4, ch = idx & 15;
            *(short8v*)&As[r][(ch ^ (r & 15)) * 8] = a[it];
        }
    }
    __syncthreads();

    int mrow = wid * 16;
    int col = lane & 15;
    int kg = lane >> 4;
    floatx4 acc[8] = {};

#pragma unroll
    for (int ks = 0; ks < 4; ++ks) {
        int chb = ks * 4 + kg;
        int r0 = mrow + col;
        short8v a0 = *(short8v*)&As[r0][(chb ^ (r0 & 15)) * 8];
        short8v b[8];
#pragma unroll
        for (int ni = 0; ni < 8; ++ni) {
            int rn = ni * 16 + col;
            b[ni] = *(short8v*)&Ws[rn][(chb ^ (rn & 15)) * 8];
        }
#pragma unroll
        for (int ni = 0; ni < 8; ++ni)
            acc[ni] = __builtin_amdgcn_mfma_f32_16x16x32_bf16(b[ni], a0, acc[ni], 0, 0, 0);
    }

    // epilogue: lane holds features ni*16+kg*4+{0..3} of node (mrow+col)
    int node = row0 + mrow + col;
    bool ok = node < M;
    float esp = 0.f, edp = 0.f;
#pragma unroll
    for (int ni = 0; ni < 8; ++ni) {
        floatx4 v = acc[ni];
        float4 sv = *(const float4*)(a_s + ni * 16 + kg * 4);
        float4 dv = *(const float4*)(a_d + ni * 16 + kg * 4);
        esp += v[0] * sv.x + v[1] * sv.y + v[2] * sv.z + v[3] * sv.w;
        edp += v[0] * dv.x + v[1] * dv.y + v[2] * dv.z + v[3] * dv.w;
        int lo = __builtin_amdgcn_cvt_pk_fp8_f32(v[0], v[1], 0, false);
        int dw = __builtin_amdgcn_cvt_pk_fp8_f32(v[2], v[3], lo, true);
        if (ok) *(int*)&Cf8[(size_t)node * 128 + ni * 16 + kg * 4] = dw;
    }
    esp += __shfl_xor(esp, 16); esp += __shfl_xor(esp, 32);
    edp += __shfl_xor(edp, 16); edp += __shfl_xor(edp, 32);
    if (ok && kg == 0) { es[node] = esp; ed[node] = edp; }
}

// ---------------- per-node softmax + aggregation (wave per node) ----------------

__global__ __launch_bounds__(256) void k_aggregate(const unsigned char* __restrict__ hf8,
                                                   const float* __restrict__ es,
                                                   const float* __restrict__ ed,
                                                   const int* __restrict__ csr_src,
                                                   const int* __restrict__ offs,
                                                   const float* __restrict__ bias,
                                                   ushort* __restrict__ out, int N) {
    __shared__ __align__(16) float2 pe[4][64];
    int wid  = threadIdx.x >> 6;
    int lane = threadIdx.x & 63;
    int w = (blockIdx.x * 256 + threadIdx.x) >> 6;
    if (w >= N) return;
    int beg = offs[w], end = offs[w + 1];
    float edi = ed[w];
    int grp = lane >> 4, fc = lane & 15;
    const unsigned char* hbase = hf8 + fc * 8;   // per-lane feature base

    float s_lane = 0.f;
    float acc[8] = {0.f, 0.f, 0.f, 0.f, 0.f, 0.f, 0.f, 0.f};

    for (int tb = beg; tb < end; tb += WAVE) {
        int cnt = end - tb; if (cnt > WAVE) cnt = WAVE;

        float p = 0.f;
        int sj = 0;
        if (lane < cnt) {
            sj = csr_src[tb + lane];
            float t = es[sj] + edi;
            float e = (t > 0.f) ? t : 0.2f * t;
            p = __expf(e);
        }
        s_lane += p;
        pe[wid][lane] = make_float2(p, __int_as_float(sj << 7));  // pre-shifted byte offset
        asm volatile("s_waitcnt lgkmcnt(0)" ::: "memory");

        __builtin_amdgcn_s_setprio(1);
        int cnt4 = (cnt + 3) & ~3;
        for (int k = 0; k < cnt4; k += 4) {
            float2 pr = pe[wid][k + grp];
            float p_ = pr.x;
            int off = __float_as_int(pr.y);
            uint2 v = *(const uint2*)(hbase + off);
            floatx2 f0 = __builtin_amdgcn_cvt_pk_f32_fp8(v.x, false);
            floatx2 f1 = __builtin_amdgcn_cvt_pk_f32_fp8(v.x, true);
            floatx2 f2 = __builtin_amdgcn_cvt_pk_f32_fp8(v.y, false);
            floatx2 f3 = __builtin_amdgcn_cvt_pk_f32_fp8(v.y, true);
            acc[0] += p_ * f0.x; acc[1] += p_ * f0.y;
            acc[2] += p_ * f1.x; acc[3] += p_ * f1.y;
            acc[4] += p_ * f2.x; acc[5] += p_ * f2.y;
            acc[6] += p_ * f3.x; acc[7] += p_ * f3.y;
        }
        __builtin_amdgcn_s_setprio(0);
    }

    float s = s_lane;
#pragma unroll
    for (int o = 32; o; o >>= 1) s += __shfl_xor(s, o);

#pragma unroll
    for (int i = 0; i < 8; ++i) {
        acc[i] += __shfl_xor(acc[i], 16);
        acc[i] += __shfl_xor(acc[i], 32);
    }

    if (grp == 0) {
        float rinv = 1.f / s;
        float4 b0 = *(const float4*)(bias + fc * 8);
        float4 b1 = *(const float4*)(bias + fc * 8 + 4);
        float o_[8];
        o_[0] = fmaxf(acc[0] * rinv + b0.x, 0.f);
        o_[1] = fmaxf(acc[1] * rinv + b0.y, 0.f);
        o_[2] = fmaxf(acc[2] * rinv + b0.z, 0.f);
        o_[3] = fmaxf(acc[3] * rinv + b0.w, 0.f);
        o_[4] = fmaxf(acc[4] * rinv + b1.x, 0.f);
        o_[5] = fmaxf(acc[5] * rinv + b1.y, 0.f);
        o_[6] = fmaxf(acc[6] * rinv + b1.z, 0.f);
        o_[7] = fmaxf(acc[7] * rinv + b1.w, 0.f);
        uint4 pk;
        pk.x = (unsigned)f2bf(o_[0]) | ((unsigned)f2bf(o_[1]) << 16);
        pk.y = (unsigned)f2bf(o_[2]) | ((unsigned)f2bf(o_[3]) << 16);
        pk.z = (unsigned)f2bf(o_[4]) | ((unsigned)f2bf(o_[5]) << 16);
        pk.w = (unsigned)f2bf(o_[6]) | ((unsigned)f2bf(o_[7]) << 16);
        *(uint4*)(out + (size_t)w * 128 + fc * 8) = pk;
    }
}

// ---------------- pooling: 32-node chunks, unrolled fast path ----------------

__global__ __launch_bounds__(128) void k_poolsum(const ushort* __restrict__ h,
                                                 const int* __restrict__ batch,
                                                 float* __restrict__ sums,
                                                 int* __restrict__ cnt, int N) {
    int t = threadIdx.x;
    int base = blockIdx.x * PCHUNK;
    if (base >= N) return;

    int cur = batch[base];
    float acc = 0.f;
    int cnum = 0;

    if (base + PCHUNK <= N) {
#pragma unroll
        for (int k = 0; k < PCHUNK; ++k) {
            int i = base + k;
            int g = batch[i];
            float v = bf2f(h[(size_t)i * 128 + t]);
            if (g != cur) {
                atomicAdd(&sums[cur * 128 + t], acc);
                if (t == 0) atomicAdd(&cnt[cur], cnum);
                acc = 0.f; cnum = 0; cur = g;
            }
            acc += v;
            ++cnum;
        }
    } else {
        for (int i = base; i < N; ++i) {
            int g = batch[i];
            float v = bf2f(h[(size_t)i * 128 + t]);
            if (g != cur) {
                atomicAdd(&sums[cur * 128 + t], acc);
                if (t == 0) atomicAdd(&cnt[cur], cnum);
                acc = 0.f; cnum = 0; cur = g;
            }
            acc += v;
            ++cnum;
        }
    }
    atomicAdd(&sums[cur * 128 + t], acc);
    if (t == 0) atomicAdd(&cnt[cur], cnum);
}

__global__ __launch_bounds__(64) void k_head(const float* __restrict__ sums,
                                             const int* __restrict__ cnt,
                                             const float* __restrict__ gf,
                                             const float* __restrict__ linW,
                                             const float* __restrict__ linb,
                                             float* __restrict__ out) {
    int g = blockIdx.x, t = threadIdx.x;
    __shared__ float feat[144];
    float c = fmaxf((float)cnt[g], 1.f);
    for (int k = t; k < 128; k += 64) feat[k] = sums[g * 128 + k] / c;
    if (t < 16) feat[128 + t] = gf[g * 16 + t];
    __syncthreads();
    if (t < 10) {
        float acc = linb[t];
        for (int k = 0; k < 144; ++k) acc += feat[k] * linW[k * 10 + t];
        out[g * 10 + t] = acc;
    }
}

// ---------------- launch ----------------

extern "C" void kernel_launch(void* const* d_in, const int* in_sizes, int n_in,
                              void* d_out, int out_size, void* d_ws, size_t ws_size,
                              hipStream_t stream) {
    const float* x    = (const float*)d_in[0];
    const int*   eidx = (const int*)d_in[1];
    const int*   batch = (const int*)d_in[2];
    const float* gf   = (const float*)d_in[3];
    const float* W1   = (const float*)d_in[4];
    const float* as1  = (const float*)d_in[5];
    const float* ad1  = (const float*)d_in[6];
    const float* b1   = (const float*)d_in[7];
    const float* W2   = (const float*)d_in[8];
    const float* as2  = (const float*)d_in[9];
    const float* ad2  = (const float*)d_in[10];
    const float* b2   = (const float*)d_in[11];
    const float* linW = (const float*)d_in[12];
    const float* linb = (const float*)d_in[13];
    float* out = (float*)d_out;

    const int N = in_sizes[0] / 128;
    const int E = in_sizes[1] / 2;
    const int Etot = E + N;
    const int B = (N + 255) >> 8;
    const int* srcp = eidx;
    const int* dstp = eidx + E;

    char* ws = (char*)d_ws;
    size_t off = 0;
    auto alloc = [&](size_t bytes) -> void* {
        void* p = ws + off;
        off += (bytes + 255) & ~(size_t)255;
        return p;
    };
    unsigned char* hAf8 = (unsigned char*)alloc((size_t)N * 128);  // GEMM out (fp8, gather-only)
    ushort* hBb   = (ushort*)alloc((size_t)N * 128 * 2);           // aggregate out (bf16)
    float*  esed  = (float*)alloc((size_t)2 * N * 4);
    float*  es = esed, *ed = esed + N;
    ushort* Wt1   = (ushort*)alloc(16384 * 2);
    ushort* Wt2   = (ushort*)alloc(16384 * 2);
    int*    offs  = (int*)alloc((size_t)(N + 1) * 4);
    int*    bbase = (int*)alloc((size_t)B * 4);
    int*    bucket= (int*)alloc((size_t)B * BUCKET_CAP * 4);
    int*    csr   = (int*)alloc((size_t)Etot * 4);
    int nzero = B + 64 * 128 + 64;
    int*    zreg  = (int*)alloc((size_t)nzero * 4);
    int*    bcnt  = zreg;
    float*  psums = (float*)(zreg + B);
    int*    pcnt  = zreg + B + 64 * 128;

    // ---- init (zero scratch + W transpose) ----
    int zblocks = (nzero + 255) / 256;
    k_init<<<zblocks + 2, 256, 0, stream>>>(zreg, nzero, zblocks, W1, W2, Wt1, Wt2);

    // ---- CSR build ----
    k_bucket<<<(Etot + EPB - 1) / EPB, 256, 0, stream>>>(srcp, dstp, E, N, B, bcnt, bucket);
    k_bscan<<<1, 512, 0, stream>>>(bcnt, bbase, B, Etot, offs, N);
    k_csr<<<B, 256, 0, stream>>>(bcnt, bbase, bucket, offs, csr, N);

    int gblocks = (N + 63) / 64;
    int wblocks = ((size_t)N * 64 + 255) / 256;

    // ---- layer 1 ----
    k_gemm_mfma<true><<<gblocks, 256, 0, stream>>>(x, Wt1, as1, ad1, hAf8, es, ed, N);
    k_aggregate<<<wblocks, 256, 0, stream>>>(hAf8, es, ed, csr, offs, b1, hBb, N);

    // ---- layer 2 ----
    k_gemm_mfma<false><<<gblocks, 256, 0, stream>>>(hBb, Wt2, as2, ad2, hAf8, es, ed, N);
    k_aggregate<<<wblocks, 256, 0, stream>>>(hAf8, es, ed, csr, offs, b2, hBb, N);

    // ---- pool + head ----
    k_poolsum<<<(N + PCHUNK - 1) / PCHUNK, 128, 0, stream>>>(hBb, batch, psums, pcnt, N);
    k_head<<<64, 64, 0, stream>>>(psums, pcnt, gf, linW, linb, out);
}